// Round 6
// baseline (1332.479 us; speedup 1.0000x reference)
//
#include <hip/hip_runtime.h>
#include <cstdint>
#include <cstddef>
#include <math.h>

#define L_SEQ 4096
#define D_DIM 768
#define B_SZ 8
#define M_ROWS (B_SZ * L_SEQ)   // 32768
#define CHUNK 64

typedef __bf16 bf16x8 __attribute__((ext_vector_type(8)));
typedef float floatx4 __attribute__((ext_vector_type(4)));

#define GLP(p)  ((__attribute__((address_space(1))) const void*)(const void*)(p))
#define LDSP(p) ((__attribute__((address_space(3))) void*)(void*)(p))

// ---------------- LayerNorm: one block per row (fp32 in -> bf16 out) ----------------
__global__ __launch_bounds__(256) void ln_kernel(const float* __restrict__ x,
                                                 const float* __restrict__ g,
                                                 const float* __restrict__ b,
                                                 __bf16* __restrict__ xn) {
  __shared__ float red[256];
  const int tid = threadIdx.x;
  const size_t row = blockIdx.x;
  const float* xr = x + row * D_DIM;
  float v0 = xr[tid];
  float v1 = xr[tid + 256];
  float v2 = xr[tid + 512];
  red[tid] = v0 + v1 + v2;
  __syncthreads();
  for (int off = 128; off > 0; off >>= 1) {
    if (tid < off) red[tid] += red[tid + off];
    __syncthreads();
  }
  float mu = red[0] * (1.0f / D_DIM);
  __syncthreads();
  float d0 = v0 - mu, d1 = v1 - mu, d2 = v2 - mu;
  red[tid] = d0 * d0 + d1 * d1 + d2 * d2;
  __syncthreads();
  for (int off = 128; off > 0; off >>= 1) {
    if (tid < off) red[tid] += red[tid + off];
    __syncthreads();
  }
  float rs = rsqrtf(red[0] * (1.0f / D_DIM) + 1e-5f);
  __bf16* xo = xn + row * D_DIM;
  xo[tid]       = (__bf16)(d0 * rs * g[tid]       + b[tid]);
  xo[tid + 256] = (__bf16)(d1 * rs * g[tid + 256] + b[tid + 256]);
  xo[tid + 512] = (__bf16)(d2 * rs * g[tid + 512] + b[tid + 512]);
}

// =====================================================================
// 256x256 / BK=64 / 8-wave pipelined MFMA GEMM.
// Phase form (m201): {ds_reads for LATER phases; 2 stage loads; BARR;
//                     LGKM0; setprio(1); 16 MFMA; setprio(0); BARR}
// INVARIANT: any LDS region read at a phase top is only DMA-overwritten by
// stages issued in phases AFTER that phase's closing barrier; the phase's
// LGKM0 (between the two barriers) pins read completion first.
// The prologue obeys the same invariant via its trailing LGKM0+BARR (the
// R3/R5 bug was tile-0 Pa's A-h0 DMA racing the prologue RD_AL).
// Residency: ONE counted vmcnt per tile (end of Pb, before its closing
// barrier) retires the NEXT buffer's 8 staging loads for every wave; the
// barrier publishes them; first reads of that buffer are at Pc top.
//  MODE 0: proj   A=xn(Mx768),  Bt=Wi^T(1536x768).  col<768->xg, else silu->zg
//  MODE 1: fused conv fwd+bwd-natural. A[(b,l)][k*768+i]=xg[b,l+k-1,i] (0-pad)
//  MODE 3: out    A=y(Mx768), Bt=Wo^T, +bias+resid -> fp32
// LDS: 2 bufs x (A 256x64 + B 256x64) bf16 = 131072 B. 1 block/CU, 8 waves.
// Swizzle: phys_chunk = log_chunk ^ (row&7), applied on gload_lds SOURCE addr
// (LDS dest linear) and on the ds_read addr (both-sides, rule 21).
// =====================================================================

#define VMW(n) asm volatile("s_waitcnt vmcnt(" #n ")" ::: "memory")
#define LGKM0  asm volatile("s_waitcnt lgkmcnt(0)" ::: "memory")
#define BARR   asm volatile("s_barrier" ::: "memory")
#define SP1    __builtin_amdgcn_s_setprio(1)
#define SP0    __builtin_amdgcn_s_setprio(0)
#define MF(a, b, c) __builtin_amdgcn_mfma_f32_16x16x32_bf16((a), (b), (c), 0, 0, 0)
#define LDV(off) (*(const bf16x8*)(smem + (off)))

// fragment reads (per wave). A rows: wm*128 + i*16 + l15 (+64 for hi)
#define RD_AL(BUF) do { \
  aL0k0 = LDV((BUF)*65536 + aoff + ck0);        aL0k1 = LDV((BUF)*65536 + aoff + ck1); \
  aL1k0 = LDV((BUF)*65536 + aoff + 2048 + ck0); aL1k1 = LDV((BUF)*65536 + aoff + 2048 + ck1); \
  aL2k0 = LDV((BUF)*65536 + aoff + 4096 + ck0); aL2k1 = LDV((BUF)*65536 + aoff + 4096 + ck1); \
  aL3k0 = LDV((BUF)*65536 + aoff + 6144 + ck0); aL3k1 = LDV((BUF)*65536 + aoff + 6144 + ck1); \
} while (0)

#define RD_AH(BUF) do { \
  aH0k0 = LDV((BUF)*65536 + aoff + 8192 + ck0);        aH0k1 = LDV((BUF)*65536 + aoff + 8192 + ck1); \
  aH1k0 = LDV((BUF)*65536 + aoff + 8192 + 2048 + ck0); aH1k1 = LDV((BUF)*65536 + aoff + 8192 + 2048 + ck1); \
  aH2k0 = LDV((BUF)*65536 + aoff + 8192 + 4096 + ck0); aH2k1 = LDV((BUF)*65536 + aoff + 8192 + 4096 + ck1); \
  aH3k0 = LDV((BUF)*65536 + aoff + 8192 + 6144 + ck0); aH3k1 = LDV((BUF)*65536 + aoff + 8192 + 6144 + ck1); \
} while (0)

#define RD_B01(BUF) do { \
  b0k0 = LDV((BUF)*65536 + boff + ck0);        b0k1 = LDV((BUF)*65536 + boff + ck1); \
  b1k0 = LDV((BUF)*65536 + boff + 2048 + ck0); b1k1 = LDV((BUF)*65536 + boff + 2048 + ck1); \
} while (0)

#define RD_B23(BUF) do { \
  b2k0 = LDV((BUF)*65536 + boff + 4096 + ck0); b2k1 = LDV((BUF)*65536 + boff + 4096 + ck1); \
  b3k0 = LDV((BUF)*65536 + boff + 6144 + ck0); b3k1 = LDV((BUF)*65536 + boff + 6144 + ck1); \
} while (0)

// MFMA quadrants (16 each)
#define MMPA do { \
  acc[0][0]=MF(aL0k0,b0k0,acc[0][0]); acc[0][0]=MF(aL0k1,b0k1,acc[0][0]); \
  acc[0][1]=MF(aL0k0,b1k0,acc[0][1]); acc[0][1]=MF(aL0k1,b1k1,acc[0][1]); \
  acc[1][0]=MF(aL1k0,b0k0,acc[1][0]); acc[1][0]=MF(aL1k1,b0k1,acc[1][0]); \
  acc[1][1]=MF(aL1k0,b1k0,acc[1][1]); acc[1][1]=MF(aL1k1,b1k1,acc[1][1]); \
  acc[2][0]=MF(aL2k0,b0k0,acc[2][0]); acc[2][0]=MF(aL2k1,b0k1,acc[2][0]); \
  acc[2][1]=MF(aL2k0,b1k0,acc[2][1]); acc[2][1]=MF(aL2k1,b1k1,acc[2][1]); \
  acc[3][0]=MF(aL3k0,b0k0,acc[3][0]); acc[3][0]=MF(aL3k1,b0k1,acc[3][0]); \
  acc[3][1]=MF(aL3k0,b1k0,acc[3][1]); acc[3][1]=MF(aL3k1,b1k1,acc[3][1]); \
} while (0)

#define MMPB do { \
  acc[0][2]=MF(aL0k0,b2k0,acc[0][2]); acc[0][2]=MF(aL0k1,b2k1,acc[0][2]); \
  acc[0][3]=MF(aL0k0,b3k0,acc[0][3]); acc[0][3]=MF(aL0k1,b3k1,acc[0][3]); \
  acc[1][2]=MF(aL1k0,b2k0,acc[1][2]); acc[1][2]=MF(aL1k1,b2k1,acc[1][2]); \
  acc[1][3]=MF(aL1k0,b3k0,acc[1][3]); acc[1][3]=MF(aL1k1,b3k1,acc[1][3]); \
  acc[2][2]=MF(aL2k0,b2k0,acc[2][2]); acc[2][2]=MF(aL2k1,b2k1,acc[2][2]); \
  acc[2][3]=MF(aL2k0,b3k0,acc[2][3]); acc[2][3]=MF(aL2k1,b3k1,acc[2][3]); \
  acc[3][2]=MF(aL3k0,b2k0,acc[3][2]); acc[3][2]=MF(aL3k1,b2k1,acc[3][2]); \
  acc[3][3]=MF(aL3k0,b3k0,acc[3][3]); acc[3][3]=MF(aL3k1,b3k1,acc[3][3]); \
} while (0)

#define MMPC do { \
  acc[4][0]=MF(aH0k0,b0k0,acc[4][0]); acc[4][0]=MF(aH0k1,b0k1,acc[4][0]); \
  acc[4][1]=MF(aH0k0,b1k0,acc[4][1]); acc[4][1]=MF(aH0k1,b1k1,acc[4][1]); \
  acc[5][0]=MF(aH1k0,b0k0,acc[5][0]); acc[5][0]=MF(aH1k1,b0k1,acc[5][0]); \
  acc[5][1]=MF(aH1k0,b1k0,acc[5][1]); acc[5][1]=MF(aH1k1,b1k1,acc[5][1]); \
  acc[6][0]=MF(aH2k0,b0k0,acc[6][0]); acc[6][0]=MF(aH2k1,b0k1,acc[6][0]); \
  acc[6][1]=MF(aH2k0,b1k0,acc[6][1]); acc[6][1]=MF(aH2k1,b1k1,acc[6][1]); \
  acc[7][0]=MF(aH3k0,b0k0,acc[7][0]); acc[7][0]=MF(aH3k1,b0k1,acc[7][0]); \
  acc[7][1]=MF(aH3k0,b1k0,acc[7][1]); acc[7][1]=MF(aH3k1,b1k1,acc[7][1]); \
} while (0)

#define MMPD do { \
  acc[4][2]=MF(aH0k0,b2k0,acc[4][2]); acc[4][2]=MF(aH0k1,b2k1,acc[4][2]); \
  acc[4][3]=MF(aH0k0,b3k0,acc[4][3]); acc[4][3]=MF(aH0k1,b3k1,acc[4][3]); \
  acc[5][2]=MF(aH1k0,b2k0,acc[5][2]); acc[5][2]=MF(aH1k1,b2k1,acc[5][2]); \
  acc[5][3]=MF(aH1k0,b3k0,acc[5][3]); acc[5][3]=MF(aH1k1,b3k1,acc[5][3]); \
  acc[6][2]=MF(aH2k0,b2k0,acc[6][2]); acc[6][2]=MF(aH2k1,b2k1,acc[6][2]); \
  acc[6][3]=MF(aH2k0,b3k0,acc[6][3]); acc[6][3]=MF(aH2k1,b3k1,acc[6][3]); \
  acc[7][2]=MF(aH3k0,b2k0,acc[7][2]); acc[7][2]=MF(aH3k1,b2k1,acc[7][2]); \
  acc[7][3]=MF(aH3k0,b3k0,acc[7][3]); acc[7][3]=MF(aH3k1,b3k1,acc[7][3]); \
} while (0)

// staging: A unit h covers rows {h*64..h*64+63 (p0), 128+h*64.. (p1)}
// dest (linear LDS): A: h*8192 + p*16384; B: 32768 + h*16384 + p*8192
#define STA(h, p, tkt, BUF) do { \
  int _off; \
  if (MODE == 1) { \
    const int _kb = ((tkt) * 43) >> 9;                 /* tkt/12 for tkt<48 */ \
    const int _io = (((tkt) - _kb * 12) << 6) + (_kb - 1) * D_DIM; \
    _off = ((unsigned)(lv##h##p + _kb - 1) < (unsigned)L_SEQ) ? (oa##h##p + _io) : zrel; \
  } else { \
    _off = oa##h##p + (tkt) * 64; \
  } \
  __builtin_amdgcn_global_load_lds(GLP(A + _off), \
      LDSP(smem + (BUF)*65536 + (h)*8192 + (p)*16384 + dstw), 16, 0, 0); \
} while (0)

#define STB(h, p, tkt, BUF) \
  __builtin_amdgcn_global_load_lds(GLP(Bt + ob##h##p + (tkt) * 64), \
      LDSP(smem + (BUF)*65536 + 32768 + (h)*16384 + (p)*8192 + dstw), 16, 0, 0)

// One K-tile = 4 phases. Stage plan (tile T stages T+2): Pa/Pb: A; Pc/Pd: B.
// Read plan: Pa-top: aH(T)+b23(T); Pc-top: aL(T+1); Pd-top: b01(T+1).
// VMW(VB) after MMPB, before Pb's closing barrier: retires buffer T+1's 8
// staging loads (outstanding then = those 8 + the 4 T+2 stages just issued).
#define TILE(T, BUF, VB, DOST, DORD) do { \
  /* Pa */ \
  RD_AH(BUF); RD_B23(BUF); \
  if (DOST) { STA(0, 0, (T) + 2, BUF); STA(0, 1, (T) + 2, BUF); } \
  BARR; LGKM0; SP1; MMPA; SP0; BARR; \
  /* Pb */ \
  if (DOST) { STA(1, 0, (T) + 2, BUF); STA(1, 1, (T) + 2, BUF); } \
  BARR; LGKM0; SP1; MMPB; SP0; VMW(VB); BARR; \
  /* Pc */ \
  if (DORD) { RD_AL((BUF) ^ 1); } \
  if (DOST) { STB(0, 0, (T) + 2, BUF); STB(0, 1, (T) + 2, BUF); } \
  BARR; LGKM0; SP1; MMPC; SP0; BARR; \
  /* Pd */ \
  if (DORD) { RD_B01((BUF) ^ 1); } \
  if (DOST) { STB(1, 0, (T) + 2, BUF); STB(1, 1, (T) + 2, BUF); } \
  BARR; LGKM0; SP1; MMPD; SP0; BARR; \
} while (0)

template<int MODE, int NT, int NN>
__global__ __launch_bounds__(512) void gemm256_kernel(
    const __bf16* __restrict__ A, const __bf16* __restrict__ Bt,
    const float* __restrict__ bias_lo, const float* __restrict__ bias_hi,
    const float* __restrict__ resid,
    __bf16* __restrict__ out0, __bf16* __restrict__ out1,
    float* __restrict__ outf, int zrel) {
  extern __shared__ char smem[];
  constexpr int K = NT * 64;
  constexpr int nwg = NN * (M_ROWS / 256);
  constexpr int cpx = nwg / 8;               // nwg % 8 == 0 for all modes
  const int bid = blockIdx.x;
  const int wgs = (bid & 7) * cpx + (bid >> 3);   // bijective XCD swizzle
  const int tileN = wgs % NN;
  const int tileM = wgs / NN;
  const int tid  = (int)threadIdx.x;
  const int w    = tid >> 6;
  const int lane = tid & 63;
  const int l15  = lane & 15;
  const int quad = lane >> 4;
  const int wm   = w >> 2;                   // 2 waves in M
  const int wn   = w & 3;                    // 4 waves in N

  const int srow = tid >> 3;                 // 0..63 (staging row within unit)
  const int ce   = ((tid & 7) ^ (srow & 7)) << 3;  // pre-swizzled source col
  const int dstw = w << 10;

  const int aoff = (wm * 128 + l15) * 128;
  const int boff = 32768 + (wn * 64 + l15) * 128;
  const int ck0  = (quad ^ (l15 & 7)) << 4;
  const int ck1  = ((4 | quad) ^ (l15 & 7)) << 4;

  // 32-bit element offsets (saddr + voffset form)
  const int g00 = tileM * 256 + srow;        // A h0p0: rows 0-63
  const int g10 = g00 + 64;                  // h1p0: 64-127
  const int g01 = g00 + 128;                 // h0p1: 128-191
  const int g11 = g00 + 192;                 // h1p1: 192-255
  int oa00, oa01, oa10, oa11;
  int lv00 = 0, lv01 = 0, lv10 = 0, lv11 = 0;
  if (MODE == 1) {
    oa00 = g00 * D_DIM + ce; lv00 = g00 & (L_SEQ - 1);
    oa01 = g01 * D_DIM + ce; lv01 = g01 & (L_SEQ - 1);
    oa10 = g10 * D_DIM + ce; lv10 = g10 & (L_SEQ - 1);
    oa11 = g11 * D_DIM + ce; lv11 = g11 & (L_SEQ - 1);
  } else {
    oa00 = g00 * K + ce;
    oa01 = g01 * K + ce;
    oa10 = g10 * K + ce;
    oa11 = g11 * K + ce;
  }
  const int ob00 = (tileN * 256 +   0 + srow) * K + ce;
  const int ob01 = (tileN * 256 +  64 + srow) * K + ce;
  const int ob10 = (tileN * 256 + 128 + srow) * K + ce;
  const int ob11 = (tileN * 256 + 192 + srow) * K + ce;

  bf16x8 aL0k0, aL0k1, aL1k0, aL1k1, aL2k0, aL2k1, aL3k0, aL3k1;
  bf16x8 aH0k0, aH0k1, aH1k0, aH1k1, aH2k0, aH2k1, aH3k0, aH3k1;
  bf16x8 b0k0, b0k1, b1k0, b1k1, b2k0, b2k1, b3k0, b3k1;
  floatx4 acc[8][4];
#pragma unroll
  for (int i = 0; i < 8; ++i)
#pragma unroll
    for (int j = 0; j < 4; ++j)
#pragma unroll
      for (int r = 0; r < 4; ++r) acc[i][j][r] = 0.0f;

  // prologue: fully stage tiles 0 and 1 (16 loads); retire tile0 for ALL
  // waves (VMW own-loads + BARR publishes every wave's DMA) BEFORE any read.
  STA(0, 0, 0, 0); STA(0, 1, 0, 0); STA(1, 0, 0, 0); STA(1, 1, 0, 0);
  STB(0, 0, 0, 0); STB(0, 1, 0, 0); STB(1, 0, 0, 0); STB(1, 1, 0, 0);
  STA(0, 0, 1, 1); STA(0, 1, 1, 1); STA(1, 0, 1, 1); STA(1, 1, 1, 1);
  STB(0, 0, 1, 1); STB(0, 1, 1, 1); STB(1, 0, 1, 1); STB(1, 1, 1, 1);
  VMW(8);                 // own tile0 loads retired (tile1's 8 may fly)
  BARR;                   // ...now ALL waves' tile0 DMAs are in LDS
  RD_AL(0); RD_B01(0);    // first fragments (consumed by MMPA of tile 0)
  LGKM0;                  // prologue reads complete BEFORE tile0 Pa can issue
  BARR;                   // the A-h0 overwrite DMA (R3/R5 race fix)

#pragma unroll 1
  for (int T = 0; T <= NT - 4; T += 2) {
    TILE(T,     0, 4, 1, 1);
    TILE(T + 1, 1, 4, 1, 1);
  }
  TILE(NT - 2, 0, 0, 0, 1);    // drain: tile NT-1's 8 loads must retire
  TILE(NT - 1, 1, 63, 0, 0);   // no next buffer: no wait

  // epilogue: C/D layout col=lane&15, row=quad*4+r
  const int rowb = tileM * 256 + wm * 128 + quad * 4;
  const int colb = tileN * 256 + wn * 64 + l15;
#pragma unroll
  for (int mi = 0; mi < 8; ++mi) {
#pragma unroll
    for (int nj = 0; nj < 4; ++nj) {
      const int col = colb + nj * 16;
      float bv;
      if (MODE == 3) bv = bias_lo[col];
      else bv = (col < D_DIM) ? bias_lo[col] : bias_hi[col - D_DIM];
#pragma unroll
      for (int r = 0; r < 4; ++r) {
        const int row = rowb + mi * 16 + r;
        float v = acc[mi][nj][r] + bv;
        if (MODE == 3) {
          const size_t o = (size_t)row * D_DIM + col;
          outf[o] = v + resid[o];
        } else if (MODE == 0) {
          if (col < D_DIM) out0[(size_t)row * D_DIM + col] = (__bf16)v;
          else out1[(size_t)row * D_DIM + (col - D_DIM)] = (__bf16)(v / (1.0f + expf(-v)));
        } else {
          if (col < D_DIM) out0[(size_t)row * D_DIM + col] = (__bf16)v;
          else out1[(size_t)row * D_DIM + (col - D_DIM)] = (__bf16)v;
        }
      }
    }
  }
}

// ---------------- Chunked parallel SSM scan (tensor1 scans time-REVERSED) ----------------
__global__ __launch_bounds__(256) void scan1_kernel(
    const float* __restrict__ ap0, const float* __restrict__ bp0,
    const float* __restrict__ ap1, const float* __restrict__ bp1,
    const __bf16* __restrict__ u0, const __bf16* __restrict__ u1,
    float* __restrict__ hl) {
  int idx = blockIdx.x * 256 + threadIdx.x;   // 2*8*64*96
  int dg = idx % 96;
  int rest = idx / 96;
  int chunk = rest & 63;
  int tb = rest >> 6;
  int tensor = tb >> 3;
  int b = tb & 7;
  const float* ap = (tensor ? ap1 : ap0) + dg * 8;
  const float* bp = (tensor ? bp1 : bp0) + dg * 8;
  const __bf16* u = (tensor ? u1 : u0) +
      ((size_t)(b * L_SEQ + chunk * CHUNK + (tensor ? CHUNK - 1 : 0))) * D_DIM + dg * 8;
  const int st = tensor ? -D_DIM : D_DIM;
  float a[8], bb[8], h[8];
#pragma unroll
  for (int j = 0; j < 8; ++j) {
    a[j] = 1.0f / (1.0f + expf(-ap[j]));
    bb[j] = bp[j];
    h[j] = 0.0f;
  }
  for (int t = 0; t < CHUNK; ++t) {
    bf16x8 uv = *(const bf16x8*)u;
#pragma unroll
    for (int j = 0; j < 8; ++j) h[j] = a[j] * h[j] + bb[j] * (float)uv[j];
    u += st;
  }
  float* o = hl + (size_t)(tb * 64 + chunk) * D_DIM + dg * 8;
#pragma unroll
  for (int j = 0; j < 8; ++j) o[j] = h[j];
}

__global__ __launch_bounds__(256) void scan2_kernel(
    const float* __restrict__ ap0, const float* __restrict__ ap1,
    float* __restrict__ hl) {
  int idx = blockIdx.x * 256 + threadIdx.x;   // 2*8*768
  int d = idx % D_DIM;
  int tb = idx / D_DIM;
  int tensor = tb >> 3;
  const float* ap = tensor ? ap1 : ap0;
  float a = 1.0f / (1.0f + expf(-ap[d]));
  float aT = a * a;  aT *= aT;  aT *= aT;  aT *= aT;  aT *= aT;  aT *= aT;  // a^64
  float* p = hl + (size_t)tb * 64 * D_DIM + d + (tensor ? 63 * D_DIM : 0);
  const int st = tensor ? -D_DIM : D_DIM;
  float carry = 0.0f;
  for (int c = 0; c < 64; ++c) {
    float tmp = *p;
    *p = carry;
    carry = aT * carry + tmp;
    p += st;
  }
}

// ---------------- fused scan3 (both tensors) + gating ----------------
// pass 1: tensor0 forward, f written in-place into u0.
// pass 2: tensor1 backward; y[row] = (f[row] + bb[row]) * zg[row] written directly.
__global__ __launch_bounds__(256) void ssm_gate_kernel(
    const float* __restrict__ ap0, const float* __restrict__ bp0,
    const float* __restrict__ cp0, const float* __restrict__ dp0,
    const float* __restrict__ ap1, const float* __restrict__ bp1,
    const float* __restrict__ cp1, const float* __restrict__ dp1,
    __bf16* __restrict__ u0, const __bf16* __restrict__ u1,
    const __bf16* __restrict__ zg, __bf16* __restrict__ y,
    const float* __restrict__ hl) {
  int idx = blockIdx.x * 256 + threadIdx.x;   // 8*64*96 = 49152
  int dg = idx % 96;
  int rest = idx / 96;
  int chunk = rest & 63;
  int b = rest >> 6;
  const size_t rowbase = (size_t)(b * L_SEQ + chunk * CHUNK) * D_DIM + dg * 8;

  // ---- tensor0 forward: f = c0*h + d0*u, in place ----
  {
    const float* ap = ap0 + dg * 8;
    const float* bp = bp0 + dg * 8;
    const float* cp = cp0 + dg * 8;
    const float* dp = dp0 + dg * 8;
    const float* hp = hl + (size_t)(b * 64 + chunk) * D_DIM + dg * 8;
    float a[8], bb[8], cc[8], dd[8], h[8];
#pragma unroll
    for (int j = 0; j < 8; ++j) {
      a[j] = 1.0f / (1.0f + expf(-ap[j]));
      bb[j] = bp[j]; cc[j] = cp[j]; dd[j] = dp[j];
      h[j] = hp[j];
    }
    __bf16* p = u0 + rowbase;
    for (int t = 0; t < CHUNK; ++t) {
      bf16x8 uv = *(const bf16x8*)p;
      bf16x8 ov;
#pragma unroll
      for (int j = 0; j < 8; ++j) {
        float xv = (float)uv[j];
        h[j] = a[j] * h[j] + bb[j] * xv;
        ov[j] = (__bf16)(cc[j] * h[j] + dd[j] * xv);
      }
      *(bf16x8*)p = ov;
      p += D_DIM;
    }
  }

  // ---- tensor1 backward + gate: y = (f + bb) * zg ----
  {
    const float* ap = ap1 + dg * 8;
    const float* bp = bp1 + dg * 8;
    const float* cp = cp1 + dg * 8;
    const float* dp = dp1 + dg * 8;
    const float* hp = hl + (size_t)((8 + b) * 64 + chunk) * D_DIM + dg * 8;
    float a[8], bb[8], cc[8], dd[8], h[8];
#pragma unroll
    for (int j = 0; j < 8; ++j) {
      a[j] = 1.0f / (1.0f + expf(-ap[j]));
      bb[j] = bp[j]; cc[j] = cp[j]; dd[j] = dp[j];
      h[j] = hp[j];
    }
    const size_t tail = rowbase + (size_t)(CHUNK - 1) * D_DIM;
    const __bf16* p1 = u1 + tail;
    const __bf16* pf = u0 + tail;
    const __bf16* pz = zg + tail;
    __bf16* py = y + tail;
    for (int t = 0; t < CHUNK; ++t) {
      bf16x8 uv = *(const bf16x8*)p1;
      bf16x8 f8 = *(const bf16x8*)pf;
      bf16x8 z8 = *(const bf16x8*)pz;
      bf16x8 ov;
#pragma unroll
      for (int j = 0; j < 8; ++j) {
        float xv = (float)uv[j];
        h[j] = a[j] * h[j] + bb[j] * xv;
        float bbv = cc[j] * h[j] + dd[j] * xv;
        ov[j] = (__bf16)(((float)f8[j] + bbv) * (float)z8[j]);
      }
      *(bf16x8*)py = ov;
      p1 -= D_DIM; pf -= D_DIM; pz -= D_DIM; py -= D_DIM;
    }
  }
}

// ---------------- weight transposes (fp32 in -> bf16 out) ----------------
__global__ __launch_bounds__(256) void tr_kernel(const float* __restrict__ in,
                                                 __bf16* __restrict__ out,
                                                 int Kdim, int Ndim) {
  int idx = blockIdx.x * 256 + threadIdx.x;
  if (idx >= Kdim * Ndim) return;
  int n = idx / Kdim;
  int k = idx - n * Kdim;
  out[idx] = (__bf16)in[(size_t)k * Ndim + n];
}

// conv weight reshape; rev=1 reverses kernel taps (backward conv in natural time)
__global__ __launch_bounds__(256) void trconv_kernel(const float* __restrict__ in,
                                                     __bf16* __restrict__ out,
                                                     int rev) {
  int idx = blockIdx.x * 256 + threadIdx.x;
  if (idx >= D_DIM * 2304) return;
  int o = idx / 2304;
  int rem = idx - o * 2304;
  int k = rem / D_DIM;
  int i = rem - k * D_DIM;
  int ks = rev ? (2 - k) : k;
  out[idx] = (__bf16)in[(size_t)o * 2304 + i * 3 + ks];
}

__global__ void zero_kernel(__bf16* z) { z[threadIdx.x] = (__bf16)0.0f; }

extern "C" void kernel_launch(void* const* d_in, const int* in_sizes, int n_in,
                              void* d_out, int out_size, void* d_ws, size_t ws_size,
                              hipStream_t stream) {
  const float* x    = (const float*)d_in[0];
  const float* ln_g = (const float*)d_in[1];
  const float* ln_b = (const float*)d_in[2];
  const float* Wi   = (const float*)d_in[3];
  const float* bi   = (const float*)d_in[4];
  const float* Wf   = (const float*)d_in[5];
  const float* bfc  = (const float*)d_in[6];
  const float* af   = (const float*)d_in[7];
  const float* bfp  = (const float*)d_in[8];
  const float* cfp  = (const float*)d_in[9];
  const float* dfp  = (const float*)d_in[10];
  const float* Wb   = (const float*)d_in[11];
  const float* bbc  = (const float*)d_in[12];
  const float* ab   = (const float*)d_in[13];
  const float* bbp  = (const float*)d_in[14];
  const float* cbp  = (const float*)d_in[15];
  const float* dbp  = (const float*)d_in[16];
  const float* Wo   = (const float*)d_in[17];
  const float* bo   = (const float*)d_in[18];
  float* out = (float*)d_out;

  char* ws = (char*)d_ws;
  const size_t BLD = (size_t)B_SZ * L_SEQ * D_DIM;   // 25165824
  __bf16* ws0 = (__bf16*)(ws);                       // xn, then f
  __bf16* ws1 = (__bf16*)(ws + BLD * 2);             // xg, then y
  __bf16* ws2 = (__bf16*)(ws + BLD * 4);             // zg
  __bf16* ws3 = (__bf16*)(ws + BLD * 6);             // bb input (conv output)
  __bf16* wit  = (__bf16*)(ws + BLD * 8);            // Wi^T  (1536 x 768)
  __bf16* wcat = wit + (size_t)1536 * 768;           // fused conv weights (1536 x 2304)
  __bf16* wot  = wcat + (size_t)1536 * 2304;         // Wo^T (768 x 768)
  __bf16* zbuf = wot + (size_t)768 * 768;            // 256B zero pad for conv halo
  float* hl = (float*)wcat;                          // scan scratch aliases dead wcat
  const size_t needed = BLD * 8 +
      ((size_t)1536 * 768 + (size_t)1536 * 2304 + (size_t)768 * 768) * 2 + 256;
  if (ws_size < needed) return;

  static bool attr_done = false;
  if (!attr_done) {
    (void)hipFuncSetAttribute(reinterpret_cast<const void*>(&gemm256_kernel<0, 12, 6>),
                              hipFuncAttributeMaxDynamicSharedMemorySize, 131072);
    (void)hipFuncSetAttribute(reinterpret_cast<const void*>(&gemm256_kernel<1, 36, 6>),
                              hipFuncAttributeMaxDynamicSharedMemorySize, 131072);
    (void)hipFuncSetAttribute(reinterpret_cast<const void*>(&gemm256_kernel<3, 12, 3>),
                              hipFuncAttributeMaxDynamicSharedMemorySize, 131072);
    attr_done = true;
  }

  zero_kernel<<<1, 128, 0, stream>>>(zbuf);
  tr_kernel<<<(768 * 1536 + 255) / 256, 256, 0, stream>>>(Wi, wit, 768, 1536);
  trconv_kernel<<<(768 * 2304 + 255) / 256, 256, 0, stream>>>(Wf, wcat, 0);
  trconv_kernel<<<(768 * 2304 + 255) / 256, 256, 0, stream>>>(Wb, wcat + (size_t)768 * 2304, 1);
  tr_kernel<<<(768 * 768 + 255) / 256, 256, 0, stream>>>(Wo, wot, 768, 768);

  ln_kernel<<<M_ROWS, 256, 0, stream>>>(x, ln_g, ln_b, ws0);

  // proj: xg (ws1), zg = silu(z) (ws2)
  gemm256_kernel<0, 12, 6><<<768, 512, 131072, stream>>>(
      ws0, wit, bi, bi + 768, nullptr, ws1, ws2, nullptr, 0);

  // fused fwd+bwd conv (backward in natural order via k-reversed weights)
  gemm256_kernel<1, 36, 6><<<768, 512, 131072, stream>>>(
      ws1, wcat, bfc, bbc, nullptr, ws0, ws3, nullptr, (int)(zbuf - ws1));

  // SSM scans: tensor0 forward on ws0, tensor1 reversed-time on ws3
  scan1_kernel<<<384, 256, 0, stream>>>(af, bfp, ab, bbp, ws0, ws3, hl);
  scan2_kernel<<<48, 256, 0, stream>>>(af, ab, hl);
  ssm_gate_kernel<<<192, 256, 0, stream>>>(af, bfp, cfp, dfp, ab, bbp, cbp, dbp,
                                           ws0, ws3, ws2, ws1, hl);

  // out = y@Wo + bo + x (fp32)
  gemm256_kernel<3, 12, 3><<<384, 512, 131072, stream>>>(
      ws1, wot, bo, bo, x, nullptr, nullptr, out, 0);
}

// Round 7
// 773.457 us; speedup vs baseline: 1.7228x; 1.7228x over previous
//
#include <hip/hip_runtime.h>
#include <cstdint>
#include <cstddef>
#include <math.h>

#define L_SEQ 4096
#define D_DIM 768
#define B_SZ 8
#define M_ROWS (B_SZ * L_SEQ)   // 32768
#define CHUNK 64

typedef __bf16 bf16x8 __attribute__((ext_vector_type(8)));
typedef float floatx4 __attribute__((ext_vector_type(4)));

#define GLP(p)  ((__attribute__((address_space(1))) const void*)(const void*)(p))
#define LDSP(p) ((__attribute__((address_space(3))) void*)(void*)(p))

// ---------------- LayerNorm: one block per row (fp32 in -> bf16 out) ----------------
__global__ __launch_bounds__(256) void ln_kernel(const float* __restrict__ x,
                                                 const float* __restrict__ g,
                                                 const float* __restrict__ b,
                                                 __bf16* __restrict__ xn) {
  __shared__ float red[256];
  const int tid = threadIdx.x;
  const size_t row = blockIdx.x;
  const float* xr = x + row * D_DIM;
  float v0 = xr[tid];
  float v1 = xr[tid + 256];
  float v2 = xr[tid + 512];
  red[tid] = v0 + v1 + v2;
  __syncthreads();
  for (int off = 128; off > 0; off >>= 1) {
    if (tid < off) red[tid] += red[tid + off];
    __syncthreads();
  }
  float mu = red[0] * (1.0f / D_DIM);
  __syncthreads();
  float d0 = v0 - mu, d1 = v1 - mu, d2 = v2 - mu;
  red[tid] = d0 * d0 + d1 * d1 + d2 * d2;
  __syncthreads();
  for (int off = 128; off > 0; off >>= 1) {
    if (tid < off) red[tid] += red[tid + off];
    __syncthreads();
  }
  float rs = rsqrtf(red[0] * (1.0f / D_DIM) + 1e-5f);
  __bf16* xo = xn + row * D_DIM;
  xo[tid]       = (__bf16)(d0 * rs * g[tid]       + b[tid]);
  xo[tid + 256] = (__bf16)(d1 * rs * g[tid + 256] + b[tid + 256]);
  xo[tid + 512] = (__bf16)(d2 * rs * g[tid + 512] + b[tid + 512]);
}

// =====================================================================
// 256x256 / BK=64 / 8-wave pipelined MFMA GEMM — the R1 schedule (measured
// 221.7 us conv, MfmaUtil 46.7%, passed). Reads issue right after each
// barrier; the COMPILER emits counted lgkmcnt between reads and MFMAs
// (fine-grained overlap). 3 barriers/tile; counted vmcnt (never 0 mid-loop).
// [R6 lesson: hand-rolled per-phase lgkmcnt(0) drains = 14.8% MfmaUtil.]
//  MODE 0: proj   A=xn(Mx768),  Bt=Wi^T(1536x768).  col<768->xg, else silu->zg
//  MODE 1: fused conv fwd+bwd-natural. A[(b,l)][k*768+i]=xg[b,l+k-1,i] (0-pad)
//  MODE 3: out    A=y(Mx768), Bt=Wo^T, +bias+resid -> fp32
// LDS: 2 bufs x (A 256x64 + B 256x64) bf16 = 131072 B. 1 block/CU, 8 waves.
// Swizzle: phys_chunk = log_chunk ^ (row&7) on gload_lds SOURCE addr (LDS
// dest linear) and on the ds_read addr (both-sides, rule 21).
// =====================================================================

#define VMW(n) asm volatile("s_waitcnt vmcnt(" #n ")" ::: "memory")
#define BARR   asm volatile("s_barrier" ::: "memory")
#define MF(a, b, c) __builtin_amdgcn_mfma_f32_16x16x32_bf16((a), (b), (c), 0, 0, 0)
#define LDV(off) (*(const bf16x8*)(smem + (off)))

#define RDA(BUF, MOFF) do { \
  aR0k0 = LDV((BUF)*65536 + aoff + (MOFF) + ck0);        aR0k1 = LDV((BUF)*65536 + aoff + (MOFF) + ck1); \
  aR1k0 = LDV((BUF)*65536 + aoff + (MOFF) + 2048 + ck0); aR1k1 = LDV((BUF)*65536 + aoff + (MOFF) + 2048 + ck1); \
  aR2k0 = LDV((BUF)*65536 + aoff + (MOFF) + 4096 + ck0); aR2k1 = LDV((BUF)*65536 + aoff + (MOFF) + 4096 + ck1); \
  aR3k0 = LDV((BUF)*65536 + aoff + (MOFF) + 6144 + ck0); aR3k1 = LDV((BUF)*65536 + aoff + (MOFF) + 6144 + ck1); \
} while (0)

#define RDB01(BUF) do { \
  bN0k0 = LDV((BUF)*65536 + boff + ck0);        bN0k1 = LDV((BUF)*65536 + boff + ck1); \
  bN1k0 = LDV((BUF)*65536 + boff + 2048 + ck0); bN1k1 = LDV((BUF)*65536 + boff + 2048 + ck1); \
} while (0)

#define RDB23(BUF) do { \
  bN2k0 = LDV((BUF)*65536 + boff + 4096 + ck0); bN2k1 = LDV((BUF)*65536 + boff + 4096 + ck1); \
  bN3k0 = LDV((BUF)*65536 + boff + 6144 + ck0); bN3k1 = LDV((BUF)*65536 + boff + 6144 + ck1); \
} while (0)

#define MMQ01(AI) do { \
  acc[(AI)+0][0] = MF(aR0k0, bN0k0, acc[(AI)+0][0]); acc[(AI)+0][0] = MF(aR0k1, bN0k1, acc[(AI)+0][0]); \
  acc[(AI)+0][1] = MF(aR0k0, bN1k0, acc[(AI)+0][1]); acc[(AI)+0][1] = MF(aR0k1, bN1k1, acc[(AI)+0][1]); \
  acc[(AI)+1][0] = MF(aR1k0, bN0k0, acc[(AI)+1][0]); acc[(AI)+1][0] = MF(aR1k1, bN0k1, acc[(AI)+1][0]); \
  acc[(AI)+1][1] = MF(aR1k0, bN1k0, acc[(AI)+1][1]); acc[(AI)+1][1] = MF(aR1k1, bN1k1, acc[(AI)+1][1]); \
  acc[(AI)+2][0] = MF(aR2k0, bN0k0, acc[(AI)+2][0]); acc[(AI)+2][0] = MF(aR2k1, bN0k1, acc[(AI)+2][0]); \
  acc[(AI)+2][1] = MF(aR2k0, bN1k0, acc[(AI)+2][1]); acc[(AI)+2][1] = MF(aR2k1, bN1k1, acc[(AI)+2][1]); \
  acc[(AI)+3][0] = MF(aR3k0, bN0k0, acc[(AI)+3][0]); acc[(AI)+3][0] = MF(aR3k1, bN0k1, acc[(AI)+3][0]); \
  acc[(AI)+3][1] = MF(aR3k0, bN1k0, acc[(AI)+3][1]); acc[(AI)+3][1] = MF(aR3k1, bN1k1, acc[(AI)+3][1]); \
} while (0)

#define MMQ23(AI) do { \
  acc[(AI)+0][2] = MF(aR0k0, bN2k0, acc[(AI)+0][2]); acc[(AI)+0][2] = MF(aR0k1, bN2k1, acc[(AI)+0][2]); \
  acc[(AI)+0][3] = MF(aR0k0, bN3k0, acc[(AI)+0][3]); acc[(AI)+0][3] = MF(aR0k1, bN3k1, acc[(AI)+0][3]); \
  acc[(AI)+1][2] = MF(aR1k0, bN2k0, acc[(AI)+1][2]); acc[(AI)+1][2] = MF(aR1k1, bN2k1, acc[(AI)+1][2]); \
  acc[(AI)+1][3] = MF(aR1k0, bN3k0, acc[(AI)+1][3]); acc[(AI)+1][3] = MF(aR1k1, bN3k1, acc[(AI)+1][3]); \
  acc[(AI)+2][2] = MF(aR2k0, bN2k0, acc[(AI)+2][2]); acc[(AI)+2][2] = MF(aR2k1, bN2k1, acc[(AI)+2][2]); \
  acc[(AI)+2][3] = MF(aR2k0, bN3k0, acc[(AI)+2][3]); acc[(AI)+2][3] = MF(aR2k1, bN3k1, acc[(AI)+2][3]); \
  acc[(AI)+3][2] = MF(aR3k0, bN2k0, acc[(AI)+3][2]); acc[(AI)+3][2] = MF(aR3k1, bN2k1, acc[(AI)+3][2]); \
  acc[(AI)+3][3] = MF(aR3k0, bN3k0, acc[(AI)+3][3]); acc[(AI)+3][3] = MF(aR3k1, bN3k1, acc[(AI)+3][3]); \
} while (0)

// A stage unit h: h0 = Pa-read rows {0-63,128-191}, h1 = Pc-read rows {64-127,192-255}
#define STAGE_A_HP(h, p, tkt, BUF) do { \
  const __bf16* _s; \
  if (MODE == 1) { \
    const int _kb = ((tkt) * 43) >> 9;                       /* tkt/12 for tkt<48 */ \
    const int _io = (((tkt) - _kb * 12) << 6) + (_kb - 1) * D_DIM; \
    _s = ((unsigned)(lv##h##p + _kb - 1) < (unsigned)L_SEQ) ? (rb##h##p + _io) : zbuf; \
  } else { \
    _s = rb##h##p + (tkt) * 64; \
  } \
  __builtin_amdgcn_global_load_lds(GLP(_s), \
      LDSP(smem + (BUF)*65536 + (h)*8192 + (p)*16384 + dstw), 16, 0, 0); \
} while (0)

#define STAGE_B_HP(h, p, tkt, BUF) \
  __builtin_amdgcn_global_load_lds(GLP(pB##h##p + (tkt) * 64), \
      LDSP(smem + (BUF)*65536 + 32768 + (h)*16384 + (p)*8192 + dstw), 16, 0, 0)

// One K-tile = 4 phases. vmcnt is COUNTED (never 0 in main loop): loads stay
// 5 half-tiles in flight across barriers. 3 barriers / tile.
#define TILE(T, BUF, VA, VC, SA1, SREST) do { \
  /* Pa: quadrant (m-lo, n01) */ \
  VMW(VA); BARR; \
  RDB01(BUF); RDA(BUF, 0); \
  if (SA1) { STAGE_A_HP(1, 0, (T) + 1, (BUF) ^ 1); STAGE_A_HP(1, 1, (T) + 1, (BUF) ^ 1); } \
  __builtin_amdgcn_s_setprio(1); MMQ01(0); __builtin_amdgcn_s_setprio(0); \
  /* Pb: (m-lo, n23) */ \
  BARR; \
  RDB23(BUF); \
  if (SREST) { STAGE_A_HP(0, 0, (T) + 2, (BUF)); STAGE_A_HP(0, 1, (T) + 2, (BUF)); } \
  __builtin_amdgcn_s_setprio(1); MMQ23(0); __builtin_amdgcn_s_setprio(0); \
  /* Pc: (m-hi, n01) */ \
  VMW(VC); BARR; \
  RDA(BUF, 8192); \
  if (SREST) { STAGE_B_HP(0, 0, (T) + 2, (BUF)); STAGE_B_HP(0, 1, (T) + 2, (BUF)); } \
  __builtin_amdgcn_s_setprio(1); MMQ01(4); __builtin_amdgcn_s_setprio(0); \
  /* Pd: (m-hi, n23) */ \
  if (SREST) { STAGE_B_HP(1, 0, (T) + 2, (BUF)); STAGE_B_HP(1, 1, (T) + 2, (BUF)); } \
  __builtin_amdgcn_s_setprio(1); MMQ23(4); __builtin_amdgcn_s_setprio(0); \
} while (0)

template<int MODE, int NT, int NN>
__global__ __launch_bounds__(512) void gemm256_kernel(
    const __bf16* __restrict__ A, const __bf16* __restrict__ Bt,
    const float* __restrict__ bias_lo, const float* __restrict__ bias_hi,
    const float* __restrict__ resid,
    __bf16* __restrict__ out0, __bf16* __restrict__ out1,
    float* __restrict__ outf, const __bf16* __restrict__ zbuf) {
  extern __shared__ char smem[];
  constexpr int K = NT * 64;
  constexpr int nwg = NN * (M_ROWS / 256);
  constexpr int cpx = nwg / 8;               // nwg % 8 == 0 for all modes
  const int bid = blockIdx.x;
  const int wgs = (bid & 7) * cpx + (bid >> 3);   // bijective XCD swizzle (T1)
  const int tileN = wgs % NN;
  const int tileM = wgs / NN;
  const int tid  = (int)threadIdx.x;
  const int w    = tid >> 6;
  const int lane = tid & 63;
  const int l15  = lane & 15;
  const int quad = lane >> 4;
  const int wm   = w >> 2;                   // 2 waves in M
  const int wn   = w & 3;                    // 4 waves in N

  // staging: thread covers 16B chunk (row srow, chunk tid&7), source
  // column pre-swizzled so the linear gload_lds dest holds swizzled content
  const int srow = tid >> 3;                 // 0..63
  const int ce   = ((tid & 7) ^ (srow & 7)) << 3;  // element col (inverse swizzle)
  const int dstw = w << 10;

  // frag-read bases; (row&7)==(l15&7) for all frags -> swizzled chunk per-thread const
  const int aoff = (wm * 128 + l15) * 128;
  const int boff = 32768 + (wn * 64 + l15) * 128;
  const int ck0  = (quad ^ (l15 & 7)) << 4;
  const int ck1  = ((4 | quad) ^ (l15 & 7)) << 4;

  const __bf16* pB00 = Bt + (size_t)(tileN * 256 + srow) * K + ce;
  const __bf16* pB01 = Bt + (size_t)(tileN * 256 + 64 + srow) * K + ce;
  const __bf16* pB10 = Bt + (size_t)(tileN * 256 + 128 + srow) * K + ce;
  const __bf16* pB11 = Bt + (size_t)(tileN * 256 + 192 + srow) * K + ce;

  const __bf16 *rb00, *rb01, *rb10, *rb11;
  int lv00 = 0, lv01 = 0, lv10 = 0, lv11 = 0;
  {
    const int g00 = tileM * 256 + srow;          // A-unit h0,p0: rows 0-63
    const int g01 = tileM * 256 + 128 + srow;    // h0,p1: rows 128-191
    const int g10 = tileM * 256 + 64 + srow;     // h1,p0: rows 64-127
    const int g11 = tileM * 256 + 192 + srow;    // h1,p1: rows 192-255
    if (MODE == 1) {
      rb00 = A + (size_t)g00 * D_DIM + ce; lv00 = g00 & (L_SEQ - 1);
      rb01 = A + (size_t)g01 * D_DIM + ce; lv01 = g01 & (L_SEQ - 1);
      rb10 = A + (size_t)g10 * D_DIM + ce; lv10 = g10 & (L_SEQ - 1);
      rb11 = A + (size_t)g11 * D_DIM + ce; lv11 = g11 & (L_SEQ - 1);
    } else {
      rb00 = A + (size_t)g00 * K + ce;
      rb01 = A + (size_t)g01 * K + ce;
      rb10 = A + (size_t)g10 * K + ce;
      rb11 = A + (size_t)g11 * K + ce;
    }
  }

  bf16x8 aR0k0, aR0k1, aR1k0, aR1k1, aR2k0, aR2k1, aR3k0, aR3k1;
  bf16x8 bN0k0, bN0k1, bN1k0, bN1k1, bN2k0, bN2k1, bN3k0, bN3k1;
  floatx4 acc[8][4];
#pragma unroll
  for (int i = 0; i < 8; ++i)
#pragma unroll
    for (int j = 0; j < 4; ++j)
#pragma unroll
      for (int r = 0; r < 4; ++r) acc[i][j][r] = 0.0f;

  // prologue: stage tile0 fully + tile1 {A0,B0,B1}  (14 loads)
  STAGE_A_HP(0, 0, 0, 0); STAGE_A_HP(0, 1, 0, 0);
  STAGE_B_HP(0, 0, 0, 0); STAGE_B_HP(0, 1, 0, 0);
  STAGE_B_HP(1, 0, 0, 0); STAGE_B_HP(1, 1, 0, 0);
  STAGE_A_HP(1, 0, 0, 0); STAGE_A_HP(1, 1, 0, 0);
  STAGE_A_HP(0, 0, 1, 1); STAGE_A_HP(0, 1, 1, 1);
  STAGE_B_HP(0, 0, 1, 1); STAGE_B_HP(0, 1, 1, 1);
  STAGE_B_HP(1, 0, 1, 1); STAGE_B_HP(1, 1, 1, 1);

  for (int it = 0; it < (NT - 2) / 2; ++it) {
    const int T0 = it * 2;
    TILE(T0,     0, 8, 10, 1, 1);
    TILE(T0 + 1, 1, 8, 10, 1, 1);
  }
  TILE(NT - 2, 0, 8, 8, 1, 0);
  TILE(NT - 1, 1, 2, 0, 0, 0);

  // epilogue: C/D layout col=lane&15, row=quad*4+r
  const int rowb = tileM * 256 + wm * 128 + quad * 4;
  const int colb = tileN * 256 + wn * 64 + l15;
#pragma unroll
  for (int mi = 0; mi < 8; ++mi) {
#pragma unroll
    for (int nj = 0; nj < 4; ++nj) {
      const int col = colb + nj * 16;
      float bv;
      if (MODE == 3) bv = bias_lo[col];
      else bv = (col < D_DIM) ? bias_lo[col] : bias_hi[col - D_DIM];
#pragma unroll
      for (int r = 0; r < 4; ++r) {
        const int row = rowb + mi * 16 + r;
        float v = acc[mi][nj][r] + bv;
        if (MODE == 3) {
          const size_t o = (size_t)row * D_DIM + col;
          outf[o] = v + resid[o];
        } else if (MODE == 0) {
          if (col < D_DIM) out0[(size_t)row * D_DIM + col] = (__bf16)v;
          else out1[(size_t)row * D_DIM + (col - D_DIM)] = (__bf16)(v / (1.0f + expf(-v)));
        } else {
          if (col < D_DIM) out0[(size_t)row * D_DIM + col] = (__bf16)v;
          else out1[(size_t)row * D_DIM + (col - D_DIM)] = (__bf16)v;
        }
      }
    }
  }
}

// ---------------- Chunked parallel SSM scan (tensor1 scans time-REVERSED) ----------------
__global__ __launch_bounds__(256) void scan1_kernel(
    const float* __restrict__ ap0, const float* __restrict__ bp0,
    const float* __restrict__ ap1, const float* __restrict__ bp1,
    const __bf16* __restrict__ u0, const __bf16* __restrict__ u1,
    float* __restrict__ hl) {
  int idx = blockIdx.x * 256 + threadIdx.x;   // 2*8*64*96
  int dg = idx % 96;
  int rest = idx / 96;
  int chunk = rest & 63;
  int tb = rest >> 6;
  int tensor = tb >> 3;
  int b = tb & 7;
  const float* ap = (tensor ? ap1 : ap0) + dg * 8;
  const float* bp = (tensor ? bp1 : bp0) + dg * 8;
  const __bf16* u = (tensor ? u1 : u0) +
      ((size_t)(b * L_SEQ + chunk * CHUNK + (tensor ? CHUNK - 1 : 0))) * D_DIM + dg * 8;
  const int st = tensor ? -D_DIM : D_DIM;
  float a[8], bb[8], h[8];
#pragma unroll
  for (int j = 0; j < 8; ++j) {
    a[j] = 1.0f / (1.0f + expf(-ap[j]));
    bb[j] = bp[j];
    h[j] = 0.0f;
  }
  for (int t = 0; t < CHUNK; ++t) {
    bf16x8 uv = *(const bf16x8*)u;
#pragma unroll
    for (int j = 0; j < 8; ++j) h[j] = a[j] * h[j] + bb[j] * (float)uv[j];
    u += st;
  }
  float* o = hl + (size_t)(tb * 64 + chunk) * D_DIM + dg * 8;
#pragma unroll
  for (int j = 0; j < 8; ++j) o[j] = h[j];
}

__global__ __launch_bounds__(256) void scan2_kernel(
    const float* __restrict__ ap0, const float* __restrict__ ap1,
    float* __restrict__ hl) {
  int idx = blockIdx.x * 256 + threadIdx.x;   // 2*8*768
  int d = idx % D_DIM;
  int tb = idx / D_DIM;
  int tensor = tb >> 3;
  const float* ap = tensor ? ap1 : ap0;
  float a = 1.0f / (1.0f + expf(-ap[d]));
  float aT = a * a;  aT *= aT;  aT *= aT;  aT *= aT;  aT *= aT;  aT *= aT;  // a^64
  float* p = hl + (size_t)tb * 64 * D_DIM + d + (tensor ? 63 * D_DIM : 0);
  const int st = tensor ? -D_DIM : D_DIM;
  float carry = 0.0f;
  for (int c = 0; c < 64; ++c) {
    float tmp = *p;
    *p = carry;
    carry = aT * carry + tmp;
    p += st;
  }
}

// ---------------- fused scan3 (both tensors) + gating ----------------
// pass 1: tensor0 forward, f written in-place into u0.
// pass 2: tensor1 backward; y[row] = (f[row] + bb[row]) * zg[row] written directly.
__global__ __launch_bounds__(256) void ssm_gate_kernel(
    const float* __restrict__ ap0, const float* __restrict__ bp0,
    const float* __restrict__ cp0, const float* __restrict__ dp0,
    const float* __restrict__ ap1, const float* __restrict__ bp1,
    const float* __restrict__ cp1, const float* __restrict__ dp1,
    __bf16* __restrict__ u0, const __bf16* __restrict__ u1,
    const __bf16* __restrict__ zg, __bf16* __restrict__ y,
    const float* __restrict__ hl) {
  int idx = blockIdx.x * 256 + threadIdx.x;   // 8*64*96 = 49152
  int dg = idx % 96;
  int rest = idx / 96;
  int chunk = rest & 63;
  int b = rest >> 6;
  const size_t rowbase = (size_t)(b * L_SEQ + chunk * CHUNK) * D_DIM + dg * 8;

  // ---- tensor0 forward: f = c0*h + d0*u, in place ----
  {
    const float* ap = ap0 + dg * 8;
    const float* bp = bp0 + dg * 8;
    const float* cp = cp0 + dg * 8;
    const float* dp = dp0 + dg * 8;
    const float* hp = hl + (size_t)(b * 64 + chunk) * D_DIM + dg * 8;
    float a[8], bb[8], cc[8], dd[8], h[8];
#pragma unroll
    for (int j = 0; j < 8; ++j) {
      a[j] = 1.0f / (1.0f + expf(-ap[j]));
      bb[j] = bp[j]; cc[j] = cp[j]; dd[j] = dp[j];
      h[j] = hp[j];
    }
    __bf16* p = u0 + rowbase;
    for (int t = 0; t < CHUNK; ++t) {
      bf16x8 uv = *(const bf16x8*)p;
      bf16x8 ov;
#pragma unroll
      for (int j = 0; j < 8; ++j) {
        float xv = (float)uv[j];
        h[j] = a[j] * h[j] + bb[j] * xv;
        ov[j] = (__bf16)(cc[j] * h[j] + dd[j] * xv);
      }
      *(bf16x8*)p = ov;
      p += D_DIM;
    }
  }

  // ---- tensor1 backward + gate: y = (f + bb) * zg ----
  {
    const float* ap = ap1 + dg * 8;
    const float* bp = bp1 + dg * 8;
    const float* cp = cp1 + dg * 8;
    const float* dp = dp1 + dg * 8;
    const float* hp = hl + (size_t)((8 + b) * 64 + chunk) * D_DIM + dg * 8;
    float a[8], bb[8], cc[8], dd[8], h[8];
#pragma unroll
    for (int j = 0; j < 8; ++j) {
      a[j] = 1.0f / (1.0f + expf(-ap[j]));
      bb[j] = bp[j]; cc[j] = cp[j]; dd[j] = dp[j];
      h[j] = hp[j];
    }
    const size_t tail = rowbase + (size_t)(CHUNK - 1) * D_DIM;
    const __bf16* p1 = u1 + tail;
    const __bf16* pf = u0 + tail;
    const __bf16* pz = zg + tail;
    __bf16* py = y + tail;
    for (int t = 0; t < CHUNK; ++t) {
      bf16x8 uv = *(const bf16x8*)p1;
      bf16x8 f8 = *(const bf16x8*)pf;
      bf16x8 z8 = *(const bf16x8*)pz;
      bf16x8 ov;
#pragma unroll
      for (int j = 0; j < 8; ++j) {
        float xv = (float)uv[j];
        h[j] = a[j] * h[j] + bb[j] * xv;
        float bbv = cc[j] * h[j] + dd[j] * xv;
        ov[j] = (__bf16)(((float)f8[j] + bbv) * (float)z8[j]);
      }
      *(bf16x8*)py = ov;
      p1 -= D_DIM; pf -= D_DIM; pz -= D_DIM; py -= D_DIM;
    }
  }
}

// ---------------- weight transposes (fp32 in -> bf16 out) ----------------
__global__ __launch_bounds__(256) void tr_kernel(const float* __restrict__ in,
                                                 __bf16* __restrict__ out,
                                                 int Kdim, int Ndim) {
  int idx = blockIdx.x * 256 + threadIdx.x;
  if (idx >= Kdim * Ndim) return;
  int n = idx / Kdim;
  int k = idx - n * Kdim;
  out[idx] = (__bf16)in[(size_t)k * Ndim + n];
}

// conv weight reshape; rev=1 reverses kernel taps (backward conv in natural time)
__global__ __launch_bounds__(256) void trconv_kernel(const float* __restrict__ in,
                                                     __bf16* __restrict__ out,
                                                     int rev) {
  int idx = blockIdx.x * 256 + threadIdx.x;
  if (idx >= D_DIM * 2304) return;
  int o = idx / 2304;
  int rem = idx - o * 2304;
  int k = rem / D_DIM;
  int i = rem - k * D_DIM;
  int ks = rev ? (2 - k) : k;
  out[idx] = (__bf16)in[(size_t)o * 2304 + i * 3 + ks];
}

__global__ void zero_kernel(__bf16* z) { z[threadIdx.x] = (__bf16)0.0f; }

extern "C" void kernel_launch(void* const* d_in, const int* in_sizes, int n_in,
                              void* d_out, int out_size, void* d_ws, size_t ws_size,
                              hipStream_t stream) {
  const float* x    = (const float*)d_in[0];
  const float* ln_g = (const float*)d_in[1];
  const float* ln_b = (const float*)d_in[2];
  const float* Wi   = (const float*)d_in[3];
  const float* bi   = (const float*)d_in[4];
  const float* Wf   = (const float*)d_in[5];
  const float* bfc  = (const float*)d_in[6];
  const float* af   = (const float*)d_in[7];
  const float* bfp  = (const float*)d_in[8];
  const float* cfp  = (const float*)d_in[9];
  const float* dfp  = (const float*)d_in[10];
  const float* Wb   = (const float*)d_in[11];
  const float* bbc  = (const float*)d_in[12];
  const float* ab   = (const float*)d_in[13];
  const float* bbp  = (const float*)d_in[14];
  const float* cbp  = (const float*)d_in[15];
  const float* dbp  = (const float*)d_in[16];
  const float* Wo   = (const float*)d_in[17];
  const float* bo   = (const float*)d_in[18];
  float* out = (float*)d_out;

  char* ws = (char*)d_ws;
  const size_t BLD = (size_t)B_SZ * L_SEQ * D_DIM;   // 25165824
  __bf16* ws0 = (__bf16*)(ws);                       // xn, then f
  __bf16* ws1 = (__bf16*)(ws + BLD * 2);             // xg, then y
  __bf16* ws2 = (__bf16*)(ws + BLD * 4);             // zg
  __bf16* ws3 = (__bf16*)(ws + BLD * 6);             // bb input (conv output)
  __bf16* wit  = (__bf16*)(ws + BLD * 8);            // Wi^T  (1536 x 768)
  __bf16* wcat = wit + (size_t)1536 * 768;           // fused conv weights (1536 x 2304)
  __bf16* wot  = wcat + (size_t)1536 * 2304;         // Wo^T (768 x 768)
  __bf16* zbuf = wot + (size_t)768 * 768;            // 256B zero pad for conv halo
  float* hl = (float*)wcat;                          // scan scratch aliases dead wcat
  const size_t needed = BLD * 8 +
      ((size_t)1536 * 768 + (size_t)1536 * 2304 + (size_t)768 * 768) * 2 + 256;
  if (ws_size < needed) return;

  static bool attr_done = false;
  if (!attr_done) {
    (void)hipFuncSetAttribute(reinterpret_cast<const void*>(&gemm256_kernel<0, 12, 6>),
                              hipFuncAttributeMaxDynamicSharedMemorySize, 131072);
    (void)hipFuncSetAttribute(reinterpret_cast<const void*>(&gemm256_kernel<1, 36, 6>),
                              hipFuncAttributeMaxDynamicSharedMemorySize, 131072);
    (void)hipFuncSetAttribute(reinterpret_cast<const void*>(&gemm256_kernel<3, 12, 3>),
                              hipFuncAttributeMaxDynamicSharedMemorySize, 131072);
    attr_done = true;
  }

  zero_kernel<<<1, 128, 0, stream>>>(zbuf);
  tr_kernel<<<(768 * 1536 + 255) / 256, 256, 0, stream>>>(Wi, wit, 768, 1536);
  trconv_kernel<<<(768 * 2304 + 255) / 256, 256, 0, stream>>>(Wf, wcat, 0);
  trconv_kernel<<<(768 * 2304 + 255) / 256, 256, 0, stream>>>(Wb, wcat + (size_t)768 * 2304, 1);
  tr_kernel<<<(768 * 768 + 255) / 256, 256, 0, stream>>>(Wo, wot, 768, 768);

  ln_kernel<<<M_ROWS, 256, 0, stream>>>(x, ln_g, ln_b, ws0);

  // proj: xg (ws1), zg = silu(z) (ws2)
  gemm256_kernel<0, 12, 6><<<768, 512, 131072, stream>>>(
      ws0, wit, bi, bi + 768, nullptr, ws1, ws2, nullptr, zbuf);

  // fused fwd+bwd conv (backward in natural order via k-reversed weights)
  gemm256_kernel<1, 36, 6><<<768, 512, 131072, stream>>>(
      ws1, wcat, bfc, bbc, nullptr, ws0, ws3, nullptr, zbuf);

  // SSM scans: tensor0 forward on ws0, tensor1 reversed-time on ws3
  scan1_kernel<<<384, 256, 0, stream>>>(af, bfp, ab, bbp, ws0, ws3, hl);
  scan2_kernel<<<48, 256, 0, stream>>>(af, ab, hl);
  ssm_gate_kernel<<<192, 256, 0, stream>>>(af, bfp, cfp, dfp, ab, bbp, cbp, dbp,
                                           ws0, ws3, ws2, ws1, hl);

  // out = y@Wo + bo + x (fp32)
  gemm256_kernel<3, 12, 3><<<384, 512, 131072, stream>>>(
      ws1, wot, bo, bo, x, nullptr, nullptr, out, zbuf);
}

// Round 10
// 725.449 us; speedup vs baseline: 1.8368x; 1.0662x over previous
//
#include <hip/hip_runtime.h>
#include <cstdint>
#include <cstddef>
#include <math.h>

#define L_SEQ 4096
#define D_DIM 768
#define B_SZ 8
#define M_ROWS (B_SZ * L_SEQ)   // 32768
#define CHUNK 64

typedef __bf16 bf16x8 __attribute__((ext_vector_type(8)));
typedef float floatx4 __attribute__((ext_vector_type(4)));

#define GLP(p)  ((__attribute__((address_space(1))) const void*)(const void*)(p))
#define LDSP(p) ((__attribute__((address_space(3))) void*)(void*)(p))

// ---------------- LayerNorm: one block per row (fp32 in -> bf16 out) ----------------
__global__ __launch_bounds__(256) void ln_kernel(const float* __restrict__ x,
                                                 const float* __restrict__ g,
                                                 const float* __restrict__ b,
                                                 __bf16* __restrict__ xn) {
  __shared__ float red[256];
  const int tid = threadIdx.x;
  const size_t row = blockIdx.x;
  const float* xr = x + row * D_DIM;
  float v0 = xr[tid];
  float v1 = xr[tid + 256];
  float v2 = xr[tid + 512];
  red[tid] = v0 + v1 + v2;
  __syncthreads();
  for (int off = 128; off > 0; off >>= 1) {
    if (tid < off) red[tid] += red[tid + off];
    __syncthreads();
  }
  float mu = red[0] * (1.0f / D_DIM);
  __syncthreads();
  float d0 = v0 - mu, d1 = v1 - mu, d2 = v2 - mu;
  red[tid] = d0 * d0 + d1 * d1 + d2 * d2;
  __syncthreads();
  for (int off = 128; off > 0; off >>= 1) {
    if (tid < off) red[tid] += red[tid + off];
    __syncthreads();
  }
  float rs = rsqrtf(red[0] * (1.0f / D_DIM) + 1e-5f);
  __bf16* xo = xn + row * D_DIM;
  xo[tid]       = (__bf16)(d0 * rs * g[tid]       + b[tid]);
  xo[tid + 256] = (__bf16)(d1 * rs * g[tid + 256] + b[tid + 256]);
  xo[tid + 512] = (__bf16)(d2 * rs * g[tid + 512] + b[tid + 512]);
}

// =====================================================================
// 256x256 / BK=64 / 8-wave pipelined MFMA GEMM — R1/R7 schedule, byte-
// identical TILE to the R7 run (773us total, conv 242us @ MfmaUtil 42%,
// passed). Reads issue right after each barrier; the COMPILER emits counted
// lgkmcnt between reads and MFMAs. 3 barriers/tile; counted vmcnt (never 0
// mid-loop). [R6 lesson: per-phase lgkmcnt(0) drains = 14.8% MfmaUtil.]
// [R8/R9 note: RDB23 Pa-hoist reverted pending a clean infra run.]
//  MODE 0: proj   A=xn(Mx768),  Bt=Wi^T(1536x768).  col<768->xg, else silu->zg
//  MODE 1: fused conv fwd+bwd-natural. A[(b,l)][k*768+i]=xg[b,l+k-1,i] (0-pad)
//  MODE 3: out    A=y(Mx768), Bt=Wo^T, +bias+resid -> fp32
// LDS: 2 bufs x (A 256x64 + B 256x64) bf16 = 131072 B. 1 block/CU, 8 waves.
// Swizzle: phys_chunk = log_chunk ^ (row&7) on gload_lds SOURCE addr (LDS
// dest linear) and on the ds_read addr (both-sides, rule 21).
// =====================================================================

#define VMW(n) asm volatile("s_waitcnt vmcnt(" #n ")" ::: "memory")
#define BARR   asm volatile("s_barrier" ::: "memory")
#define MF(a, b, c) __builtin_amdgcn_mfma_f32_16x16x32_bf16((a), (b), (c), 0, 0, 0)
#define LDV(off) (*(const bf16x8*)(smem + (off)))

#define RDA(BUF, MOFF) do { \
  aR0k0 = LDV((BUF)*65536 + aoff + (MOFF) + ck0);        aR0k1 = LDV((BUF)*65536 + aoff + (MOFF) + ck1); \
  aR1k0 = LDV((BUF)*65536 + aoff + (MOFF) + 2048 + ck0); aR1k1 = LDV((BUF)*65536 + aoff + (MOFF) + 2048 + ck1); \
  aR2k0 = LDV((BUF)*65536 + aoff + (MOFF) + 4096 + ck0); aR2k1 = LDV((BUF)*65536 + aoff + (MOFF) + 4096 + ck1); \
  aR3k0 = LDV((BUF)*65536 + aoff + (MOFF) + 6144 + ck0); aR3k1 = LDV((BUF)*65536 + aoff + (MOFF) + 6144 + ck1); \
} while (0)

#define RDB01(BUF) do { \
  bN0k0 = LDV((BUF)*65536 + boff + ck0);        bN0k1 = LDV((BUF)*65536 + boff + ck1); \
  bN1k0 = LDV((BUF)*65536 + boff + 2048 + ck0); bN1k1 = LDV((BUF)*65536 + boff + 2048 + ck1); \
} while (0)

#define RDB23(BUF) do { \
  bN2k0 = LDV((BUF)*65536 + boff + 4096 + ck0); bN2k1 = LDV((BUF)*65536 + boff + 4096 + ck1); \
  bN3k0 = LDV((BUF)*65536 + boff + 6144 + ck0); bN3k1 = LDV((BUF)*65536 + boff + 6144 + ck1); \
} while (0)

#define MMQ01(AI) do { \
  acc[(AI)+0][0] = MF(aR0k0, bN0k0, acc[(AI)+0][0]); acc[(AI)+0][0] = MF(aR0k1, bN0k1, acc[(AI)+0][0]); \
  acc[(AI)+0][1] = MF(aR0k0, bN1k0, acc[(AI)+0][1]); acc[(AI)+0][1] = MF(aR0k1, bN1k1, acc[(AI)+0][1]); \
  acc[(AI)+1][0] = MF(aR1k0, bN0k0, acc[(AI)+1][0]); acc[(AI)+1][0] = MF(aR1k1, bN0k1, acc[(AI)+1][0]); \
  acc[(AI)+1][1] = MF(aR1k0, bN1k0, acc[(AI)+1][1]); acc[(AI)+1][1] = MF(aR1k1, bN1k1, acc[(AI)+1][1]); \
  acc[(AI)+2][0] = MF(aR2k0, bN0k0, acc[(AI)+2][0]); acc[(AI)+2][0] = MF(aR2k1, bN0k1, acc[(AI)+2][0]); \
  acc[(AI)+2][1] = MF(aR2k0, bN1k0, acc[(AI)+2][1]); acc[(AI)+2][1] = MF(aR2k1, bN1k1, acc[(AI)+2][1]); \
  acc[(AI)+3][0] = MF(aR3k0, bN0k0, acc[(AI)+3][0]); acc[(AI)+3][0] = MF(aR3k1, bN0k1, acc[(AI)+3][0]); \
  acc[(AI)+3][1] = MF(aR3k0, bN1k0, acc[(AI)+3][1]); acc[(AI)+3][1] = MF(aR3k1, bN1k1, acc[(AI)+3][1]); \
} while (0)

#define MMQ23(AI) do { \
  acc[(AI)+0][2] = MF(aR0k0, bN2k0, acc[(AI)+0][2]); acc[(AI)+0][2] = MF(aR0k1, bN2k1, acc[(AI)+0][2]); \
  acc[(AI)+0][3] = MF(aR0k0, bN3k0, acc[(AI)+0][3]); acc[(AI)+0][3] = MF(aR0k1, bN3k1, acc[(AI)+0][3]); \
  acc[(AI)+1][2] = MF(aR1k0, bN2k0, acc[(AI)+1][2]); acc[(AI)+1][2] = MF(aR1k1, bN2k1, acc[(AI)+1][2]); \
  acc[(AI)+1][3] = MF(aR1k0, bN3k0, acc[(AI)+1][3]); acc[(AI)+1][3] = MF(aR1k1, bN3k1, acc[(AI)+1][3]); \
  acc[(AI)+2][2] = MF(aR2k0, bN2k0, acc[(AI)+2][2]); acc[(AI)+2][2] = MF(aR2k1, bN2k1, acc[(AI)+2][2]); \
  acc[(AI)+2][3] = MF(aR2k0, bN3k0, acc[(AI)+2][3]); acc[(AI)+2][3] = MF(aR2k1, bN3k1, acc[(AI)+2][3]); \
  acc[(AI)+3][2] = MF(aR3k0, bN2k0, acc[(AI)+3][2]); acc[(AI)+3][2] = MF(aR3k1, bN2k1, acc[(AI)+3][2]); \
  acc[(AI)+3][3] = MF(aR3k0, bN3k0, acc[(AI)+3][3]); acc[(AI)+3][3] = MF(aR3k1, bN3k1, acc[(AI)+3][3]); \
} while (0)

// A stage unit h: h0 = Pa-read rows {0-63,128-191}, h1 = Pc-read rows {64-127,192-255}
#define STAGE_A_HP(h, p, tkt, BUF) do { \
  const __bf16* _s; \
  if (MODE == 1) { \
    const int _kb = ((tkt) * 43) >> 9;                       /* tkt/12 for tkt<48 */ \
    const int _io = (((tkt) - _kb * 12) << 6) + (_kb - 1) * D_DIM; \
    _s = ((unsigned)(lv##h##p + _kb - 1) < (unsigned)L_SEQ) ? (rb##h##p + _io) : zbuf; \
  } else { \
    _s = rb##h##p + (tkt) * 64; \
  } \
  __builtin_amdgcn_global_load_lds(GLP(_s), \
      LDSP(smem + (BUF)*65536 + (h)*8192 + (p)*16384 + dstw), 16, 0, 0); \
} while (0)

#define STAGE_B_HP(h, p, tkt, BUF) \
  __builtin_amdgcn_global_load_lds(GLP(pB##h##p + (tkt) * 64), \
      LDSP(smem + (BUF)*65536 + 32768 + (h)*16384 + (p)*8192 + dstw), 16, 0, 0)

// One K-tile = 4 phases. vmcnt is COUNTED (never 0 in main loop): loads stay
// 5 half-tiles in flight across barriers. 3 barriers / tile.
#define TILE(T, BUF, VA, VC, SA1, SREST) do { \
  /* Pa: quadrant (m-lo, n01) */ \
  VMW(VA); BARR; \
  RDB01(BUF); RDA(BUF, 0); \
  if (SA1) { STAGE_A_HP(1, 0, (T) + 1, (BUF) ^ 1); STAGE_A_HP(1, 1, (T) + 1, (BUF) ^ 1); } \
  __builtin_amdgcn_s_setprio(1); MMQ01(0); __builtin_amdgcn_s_setprio(0); \
  /* Pb: (m-lo, n23) */ \
  BARR; \
  RDB23(BUF); \
  if (SREST) { STAGE_A_HP(0, 0, (T) + 2, (BUF)); STAGE_A_HP(0, 1, (T) + 2, (BUF)); } \
  __builtin_amdgcn_s_setprio(1); MMQ23(0); __builtin_amdgcn_s_setprio(0); \
  /* Pc: (m-hi, n01) */ \
  VMW(VC); BARR; \
  RDA(BUF, 8192); \
  if (SREST) { STAGE_B_HP(0, 0, (T) + 2, (BUF)); STAGE_B_HP(0, 1, (T) + 2, (BUF)); } \
  __builtin_amdgcn_s_setprio(1); MMQ01(4); __builtin_amdgcn_s_setprio(0); \
  /* Pd: (m-hi, n23) */ \
  if (SREST) { STAGE_B_HP(1, 0, (T) + 2, (BUF)); STAGE_B_HP(1, 1, (T) + 2, (BUF)); } \
  __builtin_amdgcn_s_setprio(1); MMQ23(4); __builtin_amdgcn_s_setprio(0); \
} while (0)

template<int MODE, int NT, int NN>
__global__ __launch_bounds__(512) void gemm256_kernel(
    const __bf16* __restrict__ A, const __bf16* __restrict__ Bt,
    const float* __restrict__ bias_lo, const float* __restrict__ bias_hi,
    const float* __restrict__ resid,
    __bf16* __restrict__ out0, __bf16* __restrict__ out1,
    float* __restrict__ outf, const __bf16* __restrict__ zbuf) {
  extern __shared__ char smem[];
  constexpr int K = NT * 64;
  constexpr int nwg = NN * (M_ROWS / 256);
  constexpr int cpx = nwg / 8;               // nwg % 8 == 0 for all modes
  const int bid = blockIdx.x;
  const int wgs = (bid & 7) * cpx + (bid >> 3);   // bijective XCD swizzle (T1)
  const int tileN = wgs % NN;
  const int tileM = wgs / NN;
  const int tid  = (int)threadIdx.x;
  const int w    = tid >> 6;
  const int lane = tid & 63;
  const int l15  = lane & 15;
  const int quad = lane >> 4;
  const int wm   = w >> 2;                   // 2 waves in M
  const int wn   = w & 3;                    // 4 waves in N

  // staging: thread covers 16B chunk (row srow, chunk tid&7), source
  // column pre-swizzled so the linear gload_lds dest holds swizzled content
  const int srow = tid >> 3;                 // 0..63
  const int ce   = ((tid & 7) ^ (srow & 7)) << 3;  // element col (inverse swizzle)
  const int dstw = w << 10;

  // frag-read bases; (row&7)==(l15&7) for all frags -> swizzled chunk per-thread const
  const int aoff = (wm * 128 + l15) * 128;
  const int boff = 32768 + (wn * 64 + l15) * 128;
  const int ck0  = (quad ^ (l15 & 7)) << 4;
  const int ck1  = ((4 | quad) ^ (l15 & 7)) << 4;

  const __bf16* pB00 = Bt + (size_t)(tileN * 256 + srow) * K + ce;
  const __bf16* pB01 = Bt + (size_t)(tileN * 256 + 64 + srow) * K + ce;
  const __bf16* pB10 = Bt + (size_t)(tileN * 256 + 128 + srow) * K + ce;
  const __bf16* pB11 = Bt + (size_t)(tileN * 256 + 192 + srow) * K + ce;

  const __bf16 *rb00, *rb01, *rb10, *rb11;
  int lv00 = 0, lv01 = 0, lv10 = 0, lv11 = 0;
  {
    const int g00 = tileM * 256 + srow;          // A-unit h0,p0: rows 0-63
    const int g01 = tileM * 256 + 128 + srow;    // h0,p1: rows 128-191
    const int g10 = tileM * 256 + 64 + srow;     // h1,p0: rows 64-127
    const int g11 = tileM * 256 + 192 + srow;    // h1,p1: rows 192-255
    if (MODE == 1) {
      rb00 = A + (size_t)g00 * D_DIM + ce; lv00 = g00 & (L_SEQ - 1);
      rb01 = A + (size_t)g01 * D_DIM + ce; lv01 = g01 & (L_SEQ - 1);
      rb10 = A + (size_t)g10 * D_DIM + ce; lv10 = g10 & (L_SEQ - 1);
      rb11 = A + (size_t)g11 * D_DIM + ce; lv11 = g11 & (L_SEQ - 1);
    } else {
      rb00 = A + (size_t)g00 * K + ce;
      rb01 = A + (size_t)g01 * K + ce;
      rb10 = A + (size_t)g10 * K + ce;
      rb11 = A + (size_t)g11 * K + ce;
    }
  }

  bf16x8 aR0k0, aR0k1, aR1k0, aR1k1, aR2k0, aR2k1, aR3k0, aR3k1;
  bf16x8 bN0k0, bN0k1, bN1k0, bN1k1, bN2k0, bN2k1, bN3k0, bN3k1;
  floatx4 acc[8][4];
#pragma unroll
  for (int i = 0; i < 8; ++i)
#pragma unroll
    for (int j = 0; j < 4; ++j)
#pragma unroll
      for (int r = 0; r < 4; ++r) acc[i][j][r] = 0.0f;

  // prologue: stage tile0 fully + tile1 {A0,B0,B1}  (14 loads)
  STAGE_A_HP(0, 0, 0, 0); STAGE_A_HP(0, 1, 0, 0);
  STAGE_B_HP(0, 0, 0, 0); STAGE_B_HP(0, 1, 0, 0);
  STAGE_B_HP(1, 0, 0, 0); STAGE_B_HP(1, 1, 0, 0);
  STAGE_A_HP(1, 0, 0, 0); STAGE_A_HP(1, 1, 0, 0);
  STAGE_A_HP(0, 0, 1, 1); STAGE_A_HP(0, 1, 1, 1);
  STAGE_B_HP(0, 0, 1, 1); STAGE_B_HP(0, 1, 1, 1);
  STAGE_B_HP(1, 0, 1, 1); STAGE_B_HP(1, 1, 1, 1);

  for (int it = 0; it < (NT - 2) / 2; ++it) {
    const int T0 = it * 2;
    TILE(T0,     0, 8, 10, 1, 1);
    TILE(T0 + 1, 1, 8, 10, 1, 1);
  }
  TILE(NT - 2, 0, 8, 8, 1, 0);
  TILE(NT - 1, 1, 2, 0, 0, 0);

  // epilogue: C/D layout col=lane&15, row=quad*4+r
  const int rowb = tileM * 256 + wm * 128 + quad * 4;
  const int colb = tileN * 256 + wn * 64 + l15;
#pragma unroll
  for (int mi = 0; mi < 8; ++mi) {
#pragma unroll
    for (int nj = 0; nj < 4; ++nj) {
      const int col = colb + nj * 16;
      float bv;
      if (MODE == 3) bv = bias_lo[col];
      else bv = (col < D_DIM) ? bias_lo[col] : bias_hi[col - D_DIM];
#pragma unroll
      for (int r = 0; r < 4; ++r) {
        const int row = rowb + mi * 16 + r;
        float v = acc[mi][nj][r] + bv;
        if (MODE == 3) {
          const size_t o = (size_t)row * D_DIM + col;
          outf[o] = v + resid[o];
        } else if (MODE == 0) {
          if (col < D_DIM) out0[(size_t)row * D_DIM + col] = (__bf16)v;
          else out1[(size_t)row * D_DIM + (col - D_DIM)] = (__bf16)(v / (1.0f + expf(-v)));
        } else {
          if (col < D_DIM) out0[(size_t)row * D_DIM + col] = (__bf16)v;
          else out1[(size_t)row * D_DIM + (col - D_DIM)] = (__bf16)v;
        }
      }
    }
  }
}

// ---------------- Chunked parallel SSM scan (tensor1 scans time-REVERSED) ----------------
__global__ __launch_bounds__(256) void scan1_kernel(
    const float* __restrict__ ap0, const float* __restrict__ bp0,
    const float* __restrict__ ap1, const float* __restrict__ bp1,
    const __bf16* __restrict__ u0, const __bf16* __restrict__ u1,
    float* __restrict__ hl) {
  int idx = blockIdx.x * 256 + threadIdx.x;   // 2*8*64*96
  int dg = idx % 96;
  int rest = idx / 96;
  int chunk = rest & 63;
  int tb = rest >> 6;
  int tensor = tb >> 3;
  int b = tb & 7;
  const float* ap = (tensor ? ap1 : ap0) + dg * 8;
  const float* bp = (tensor ? bp1 : bp0) + dg * 8;
  const __bf16* u = (tensor ? u1 : u0) +
      ((size_t)(b * L_SEQ + chunk * CHUNK + (tensor ? CHUNK - 1 : 0))) * D_DIM + dg * 8;
  const int st = tensor ? -D_DIM : D_DIM;
  float a[8], bb[8], h[8];
#pragma unroll
  for (int j = 0; j < 8; ++j) {
    a[j] = 1.0f / (1.0f + expf(-ap[j]));
    bb[j] = bp[j];
    h[j] = 0.0f;
  }
  for (int t = 0; t < CHUNK; ++t) {
    bf16x8 uv = *(const bf16x8*)u;
#pragma unroll
    for (int j = 0; j < 8; ++j) h[j] = a[j] * h[j] + bb[j] * (float)uv[j];
    u += st;
  }
  float* o = hl + (size_t)(tb * 64 + chunk) * D_DIM + dg * 8;
#pragma unroll
  for (int j = 0; j < 8; ++j) o[j] = h[j];
}

__global__ __launch_bounds__(256) void scan2_kernel(
    const float* __restrict__ ap0, const float* __restrict__ ap1,
    float* __restrict__ hl) {
  int idx = blockIdx.x * 256 + threadIdx.x;   // 2*8*768
  int d = idx % D_DIM;
  int tb = idx / D_DIM;
  int tensor = tb >> 3;
  const float* ap = tensor ? ap1 : ap0;
  float a = 1.0f / (1.0f + expf(-ap[d]));
  float aT = a * a;  aT *= aT;  aT *= aT;  aT *= aT;  aT *= aT;  aT *= aT;  // a^64
  float* p = hl + (size_t)tb * 64 * D_DIM + d + (tensor ? 63 * D_DIM : 0);
  const int st = tensor ? -D_DIM : D_DIM;
  float carry = 0.0f;
  for (int c = 0; c < 64; ++c) {
    float tmp = *p;
    *p = carry;
    carry = aT * carry + tmp;
    p += st;
  }
}

// ---------------- fused scan3 (both tensors) + gating ----------------
__global__ __launch_bounds__(256) void ssm_gate_kernel(
    const float* __restrict__ ap0, const float* __restrict__ bp0,
    const float* __restrict__ cp0, const float* __restrict__ dp0,
    const float* __restrict__ ap1, const float* __restrict__ bp1,
    const float* __restrict__ cp1, const float* __restrict__ dp1,
    __bf16* __restrict__ u0, const __bf16* __restrict__ u1,
    const __bf16* __restrict__ zg, __bf16* __restrict__ y,
    const float* __restrict__ hl) {
  int idx = blockIdx.x * 256 + threadIdx.x;   // 8*64*96 = 49152
  int dg = idx % 96;
  int rest = idx / 96;
  int chunk = rest & 63;
  int b = rest >> 6;
  const size_t rowbase = (size_t)(b * L_SEQ + chunk * CHUNK) * D_DIM + dg * 8;

  // ---- tensor0 forward: f = c0*h + d0*u, in place ----
  {
    const float* ap = ap0 + dg * 8;
    const float* bp = bp0 + dg * 8;
    const float* cp = cp0 + dg * 8;
    const float* dp = dp0 + dg * 8;
    const float* hp = hl + (size_t)(b * 64 + chunk) * D_DIM + dg * 8;
    float a[8], bb[8], cc[8], dd[8], h[8];
#pragma unroll
    for (int j = 0; j < 8; ++j) {
      a[j] = 1.0f / (1.0f + expf(-ap[j]));
      bb[j] = bp[j]; cc[j] = cp[j]; dd[j] = dp[j];
      h[j] = hp[j];
    }
    __bf16* p = u0 + rowbase;
    for (int t = 0; t < CHUNK; ++t) {
      bf16x8 uv = *(const bf16x8*)p;
      bf16x8 ov;
#pragma unroll
      for (int j = 0; j < 8; ++j) {
        float xv = (float)uv[j];
        h[j] = a[j] * h[j] + bb[j] * xv;
        ov[j] = (__bf16)(cc[j] * h[j] + dd[j] * xv);
      }
      *(bf16x8*)p = ov;
      p += D_DIM;
    }
  }

  // ---- tensor1 backward + gate: y = (f + bb) * zg ----
  {
    const float* ap = ap1 + dg * 8;
    const float* bp = bp1 + dg * 8;
    const float* cp = cp1 + dg * 8;
    const float* dp = dp1 + dg * 8;
    const float* hp = hl + (size_t)((8 + b) * 64 + chunk) * D_DIM + dg * 8;
    float a[8], bb[8], cc[8], dd[8], h[8];
#pragma unroll
    for (int j = 0; j < 8; ++j) {
      a[j] = 1.0f / (1.0f + expf(-ap[j]));
      bb[j] = bp[j]; cc[j] = cp[j]; dd[j] = dp[j];
      h[j] = hp[j];
    }
    const size_t tail = rowbase + (size_t)(CHUNK - 1) * D_DIM;
    const __bf16* p1 = u1 + tail;
    const __bf16* pf = u0 + tail;
    const __bf16* pz = zg + tail;
    __bf16* py = y + tail;
    for (int t = 0; t < CHUNK; ++t) {
      bf16x8 uv = *(const bf16x8*)p1;
      bf16x8 f8 = *(const bf16x8*)pf;
      bf16x8 z8 = *(const bf16x8*)pz;
      bf16x8 ov;
#pragma unroll
      for (int j = 0; j < 8; ++j) {
        float xv = (float)uv[j];
        h[j] = a[j] * h[j] + bb[j] * xv;
        float bbv = cc[j] * h[j] + dd[j] * xv;
        ov[j] = (__bf16)(((float)f8[j] + bbv) * (float)z8[j]);
      }
      *(bf16x8*)py = ov;
      p1 -= D_DIM; pf -= D_DIM; pz -= D_DIM; py -= D_DIM;
    }
  }
}

// ------- tiled transpose (fp32 in, row-major KxN -> bf16 out, NxK) -------
// coalesced read (consecutive tx -> consecutive n) AND coalesced write
// (consecutive tx -> consecutive k). 32x32 tile via LDS, +1 pad.
__global__ __launch_bounds__(256) void tr32_kernel(const float* __restrict__ in,
                                                   __bf16* __restrict__ out,
                                                   int Kdim, int Ndim) {
  __shared__ float t[32][33];
  const int tx = threadIdx.x & 31;
  const int ty = threadIdx.x >> 5;           // 0..7
  const int n0 = blockIdx.x * 32;
  const int k0 = blockIdx.y * 32;
#pragma unroll
  for (int i = 0; i < 4; ++i)
    t[ty + i * 8][tx] = in[(size_t)(k0 + ty + i * 8) * Ndim + n0 + tx];
  __syncthreads();
#pragma unroll
  for (int i = 0; i < 4; ++i)
    out[(size_t)(n0 + ty + i * 8) * Kdim + k0 + tx] = (__bf16)t[tx][ty + i * 8];
}

// conv weight reshape; rev=1 reverses kernel taps (backward conv in natural
// time). One block per output channel o: coalesced read via LDS row buffer,
// coalesced write. out[o][k*768+i] = in[o][i][rev?2-k:k].
__global__ __launch_bounds__(256) void trconv_kernel(const float* __restrict__ in,
                                                     __bf16* __restrict__ out,
                                                     int rev) {
  __shared__ float row[2304];
  const int o = blockIdx.x;
  const float* src = in + (size_t)o * 2304;
  for (int t = threadIdx.x; t < 2304; t += 256) row[t] = src[t];
  __syncthreads();
  __bf16* dst = out + (size_t)o * 2304;
  for (int t = threadIdx.x; t < 2304; t += 256) {
    int k = t / 768;
    int i = t - k * 768;
    int ks = rev ? (2 - k) : k;
    dst[t] = (__bf16)row[i * 3 + ks];
  }
}

__global__ void zero_kernel(__bf16* z) { z[threadIdx.x] = (__bf16)0.0f; }

extern "C" void kernel_launch(void* const* d_in, const int* in_sizes, int n_in,
                              void* d_out, int out_size, void* d_ws, size_t ws_size,
                              hipStream_t stream) {
  const float* x    = (const float*)d_in[0];
  const float* ln_g = (const float*)d_in[1];
  const float* ln_b = (const float*)d_in[2];
  const float* Wi   = (const float*)d_in[3];
  const float* bi   = (const float*)d_in[4];
  const float* Wf   = (const float*)d_in[5];
  const float* bfc  = (const float*)d_in[6];
  const float* af   = (const float*)d_in[7];
  const float* bfp  = (const float*)d_in[8];
  const float* cfp  = (const float*)d_in[9];
  const float* dfp  = (const float*)d_in[10];
  const float* Wb   = (const float*)d_in[11];
  const float* bbc  = (const float*)d_in[12];
  const float* ab   = (const float*)d_in[13];
  const float* bbp  = (const float*)d_in[14];
  const float* cbp  = (const float*)d_in[15];
  const float* dbp  = (const float*)d_in[16];
  const float* Wo   = (const float*)d_in[17];
  const float* bo   = (const float*)d_in[18];
  float* out = (float*)d_out;

  char* ws = (char*)d_ws;
  const size_t BLD = (size_t)B_SZ * L_SEQ * D_DIM;   // 25165824
  __bf16* ws0 = (__bf16*)(ws);                       // xn, then f
  __bf16* ws1 = (__bf16*)(ws + BLD * 2);             // xg, then y
  __bf16* ws2 = (__bf16*)(ws + BLD * 4);             // zg
  __bf16* ws3 = (__bf16*)(ws + BLD * 6);             // bb input (conv output)
  __bf16* wit  = (__bf16*)(ws + BLD * 8);            // Wi^T  (1536 x 768)
  __bf16* wcat = wit + (size_t)1536 * 768;           // fused conv weights (1536 x 2304)
  __bf16* wot  = wcat + (size_t)1536 * 2304;         // Wo^T (768 x 768)
  __bf16* zbuf = wot + (size_t)768 * 768;            // 256B zero pad for conv halo
  float* hl = (float*)wcat;                          // scan scratch aliases dead wcat
  const size_t needed = BLD * 8 +
      ((size_t)1536 * 768 + (size_t)1536 * 2304 + (size_t)768 * 768) * 2 + 256;
  if (ws_size < needed) return;

  static bool attr_done = false;
  if (!attr_done) {
    (void)hipFuncSetAttribute(reinterpret_cast<const void*>(&gemm256_kernel<0, 12, 6>),
                              hipFuncAttributeMaxDynamicSharedMemorySize, 131072);
    (void)hipFuncSetAttribute(reinterpret_cast<const void*>(&gemm256_kernel<1, 36, 6>),
                              hipFuncAttributeMaxDynamicSharedMemorySize, 131072);
    (void)hipFuncSetAttribute(reinterpret_cast<const void*>(&gemm256_kernel<3, 12, 3>),
                              hipFuncAttributeMaxDynamicSharedMemorySize, 131072);
    attr_done = true;
  }

  zero_kernel<<<1, 128, 0, stream>>>(zbuf);
  tr32_kernel<<<dim3(1536 / 32, 768 / 32), 256, 0, stream>>>(Wi, wit, 768, 1536);
  trconv_kernel<<<768, 256, 0, stream>>>(Wf, wcat, 0);
  trconv_kernel<<<768, 256, 0, stream>>>(Wb, wcat + (size_t)768 * 2304, 1);
  tr32_kernel<<<dim3(768 / 32, 768 / 32), 256, 0, stream>>>(Wo, wot, 768, 768);

  ln_kernel<<<M_ROWS, 256, 0, stream>>>(x, ln_g, ln_b, ws0);

  // proj: xg (ws1), zg = silu(z) (ws2)
  gemm256_kernel<0, 12, 6><<<768, 512, 131072, stream>>>(
      ws0, wit, bi, bi + 768, nullptr, ws1, ws2, nullptr, zbuf);

  // fused fwd+bwd conv (backward in natural order via k-reversed weights)
  gemm256_kernel<1, 36, 6><<<768, 512, 131072, stream>>>(
      ws1, wcat, bfc, bbc, nullptr, ws0, ws3, nullptr, zbuf);

  // SSM scans: tensor0 forward on ws0, tensor1 reversed-time on ws3
  scan1_kernel<<<384, 256, 0, stream>>>(af, bfp, ab, bbp, ws0, ws3, hl);
  scan2_kernel<<<48, 256, 0, stream>>>(af, ab, hl);
  ssm_gate_kernel<<<192, 256, 0, stream>>>(af, bfp, cfp, dfp, ab, bbp, cbp, dbp,
                                           ws0, ws3, ws2, ws1, hl);

  // out = y@Wo + bo + x (fp32)
  gemm256_kernel<3, 12, 3><<<384, 512, 131072, stream>>>(
      ws1, wot, bo, bo, x, nullptr, nullptr, out, zbuf);
}